// Round 7
// baseline (304.869 us; speedup 1.0000x reference)
//
#include <hip/hip_runtime.h>
#include <hip/hip_bf16.h>
#include <cstdint>
#include <cstddef>

// B=8, L=1024, D=1024, NUM_HEADS=16, QUERY_GROUPS=4, HEAD_DIM=64, QKV_OUT=1536

typedef __bf16 bf16x8 __attribute__((ext_vector_type(8)));
typedef __bf16 bf16x4 __attribute__((ext_vector_type(4)));
typedef float floatx4 __attribute__((ext_vector_type(4)));
typedef uint32_t u32x2 __attribute__((ext_vector_type(2)));
typedef uint32_t u32x4 __attribute__((ext_vector_type(4)));

typedef unsigned int u32_g __attribute__((address_space(1)));
typedef unsigned int u32_l __attribute__((address_space(3)));

__device__ __forceinline__ void gl_lds16(const void* g, void* l) {
  __builtin_amdgcn_global_load_lds((const u32_g*)g, (u32_l*)l, 16, 0, 0);
}

// Diagonal-swizzled LDS tile (64-col rows, 8 granules of 8 bf16):
// 16B slot(row,g) = row*8 + ((g+row)&7). Zero bank conflicts (verified r6).
__device__ __forceinline__ int fidx8(int row, int g) {
  return (row * 8 + ((g + row) & 7)) * 8;
}

#define LOG2_THETA 13.287712379549449f  // log2(10000)

// ---------------- fused fp32 -> bf16 convert (x | w_qkv | w_o) ----------------
__global__ __launch_bounds__(256)
void cvt_all(const float* __restrict__ x, const float* __restrict__ wq,
             const float* __restrict__ wo, __bf16* __restrict__ out) {
  int i = blockIdx.x * 256 + threadIdx.x;  // grid covers exactly 2752512
  float4 v;
  if (i < 2097152)      v = ((const float4*)x)[i];
  else if (i < 2490368) v = ((const float4*)wq)[i - 2097152];
  else                  v = ((const float4*)wo)[i - 2490368];
  bf16x4 o = {(__bf16)v.x, (__bf16)v.y, (__bf16)v.z, (__bf16)v.w};
  ((bf16x4*)out)[i] = o;
}

// ---------------- GEMM1 fused: qkv proj + qk-norm + RoPE2D + V transpose ----
// XCD-aware mapping: bid&7 selects XCD (round-robin dispatch); each XCD owns
// bm = x mod 8 and sweeps bn consecutively -> A block-row reused in its L2.
__global__ __launch_bounds__(256, 3)
void gemm_qkv(const __bf16* __restrict__ A, const __bf16* __restrict__ Bw,
              __bf16* __restrict__ Q, __bf16* __restrict__ Ko,
              __bf16* __restrict__ Vt, const int* __restrict__ Wp) {
  __shared__ __align__(16) __bf16 sAB[16640];  // sA 8192 | sB 8192 | slack for sT
  __bf16* sA = sAB;
  __bf16* sB = sAB + 8192;
  const int tid = threadIdx.x, wave = tid >> 6, lane = tid & 63;
  const int quad = lane >> 4, lm = lane & 15;
  const int xcd = blockIdx.x & 7, tt = blockIdx.x >> 3;
  const int bm = (tt / 12) * 8 + xcd, bn = tt % 12;
  const int wm = wave & 1, wn = wave >> 1;
  const int rowA0 = bm << 7, rowB0 = bn << 7;
  const int r8 = lane >> 3;
  const int gg = ((lane & 7) - r8) & 7;  // staging granule for this lane

  floatx4 acc[4][4] = {};

  for (int k0 = 0; k0 < 1024; k0 += 64) {
    __syncthreads();
    for (int j = 0; j < 4; ++j) {
      int c = wave * 4 + j;
      gl_lds16(A + (size_t)(rowA0 + c * 8 + r8) * 1024 + k0 + gg * 8, sA + c * 512);
      gl_lds16(Bw + (size_t)(rowB0 + c * 8 + r8) * 1024 + k0 + gg * 8, sB + c * 512);
    }
    __syncthreads();
    for (int kb = 0; kb < 64; kb += 32) {
      const int gk = (kb >> 3) + quad;
      bf16x8 af[4], bfv[4];
      for (int t = 0; t < 4; ++t) {
        af[t]  = *(const bf16x8*)(sA + fidx8(wm * 64 + t * 16 + lm, gk));
        bfv[t] = *(const bf16x8*)(sB + fidx8(wn * 64 + t * 16 + lm, gk));
      }
      for (int mt = 0; mt < 4; ++mt)
        for (int nt = 0; nt < 4; ++nt)
          acc[mt][nt] = __builtin_amdgcn_mfma_f32_16x16x32_bf16(af[mt], bfv[nt],
                                                                acc[mt][nt], 0, 0, 0);
    }
  }

  __syncthreads();  // all waves' MFMA LDS reads done before sT reuse

  const int hc = bn * 2 + wn;       // head-chunk 0..23
  const int row0 = rowA0 + wm * 64; // this wave's first global row
  const int bb = row0 >> 10, l0 = row0 & 1023;

  if (hc < 20) {
    // ---- q/k: row-norm + RoPE, registers + shuffles ----
    const bool isq = hc < 16;
    const int W = Wp[0];
    const float invfA = exp2f(-(float)lm * 0.03125f * LOG2_THETA);
    const float invfB = exp2f(-(float)(lm + 16) * 0.03125f * LOG2_THETA);
    __bf16* base = isq
        ? Q + (((size_t)bb * 16 + hc) * 1024 + l0) * 64
        : Ko + (((size_t)bb * 4 + (hc - 16)) * 1024 + l0) * 64;
    const int srcA = (lane & 48) | ((2 * lm) & 15);  // quad*16 + (2i)&15
    const bool lo = lm < 8;
    for (int mt = 0; mt < 4; ++mt)
      for (int r = 0; r < 4; ++r) {
        float a0 = acc[mt][0][r], a1 = acc[mt][1][r];
        float a2 = acc[mt][2][r], a3 = acc[mt][3][r];
        float ss = a0 * a0 + a1 * a1 + a2 * a2 + a3 * a3;
        ss += __shfl_xor(ss, 1); ss += __shfl_xor(ss, 2);
        ss += __shfl_xor(ss, 4); ss += __shfl_xor(ss, 8);
        float rn = (isq ? 0.125f : 1.0f) / (sqrtf(ss) + 1e-10f);
        a0 *= rn; a1 *= rn; a2 *= rn; a3 *= rn;
        float e0 = __shfl(a0, srcA),     e1 = __shfl(a1, srcA);
        float f0 = __shfl(a0, srcA + 1), f1 = __shfl(a1, srcA + 1);
        float g0 = __shfl(a2, srcA),     g1 = __shfl(a3, srcA);
        float h0 = __shfl(a2, srcA + 1), h1 = __shfl(a3, srcA + 1);
        float x1A = lo ? e0 : e1, x2A = lo ? f0 : f1;
        float x1B = lo ? g0 : g1, x2B = lo ? h0 : h1;
        int lrow = l0 + mt * 16 + quad * 4 + r;
        int pos = lrow / W + lrow % W;
        float fA = (float)pos * invfA, fB = (float)pos * invfB;
        float cA = __cosf(fA), sA_ = __sinf(fA);
        float cB = __cosf(fB), sB_ = __sinf(fB);
        __bf16* dst = base + (size_t)(mt * 16 + quad * 4 + r) * 64;
        dst[lm]      = (__bf16)(x1A * cA - x2A * sA_);
        dst[lm + 16] = (__bf16)(x1B * cB - x2B * sB_);
        dst[lm + 32] = (__bf16)(x1A * sA_ + x2A * cA);
        dst[lm + 48] = (__bf16)(x1B * sB_ + x2B * cB);
      }
  } else {
    // ---- v: transpose 64x64 tile through wave-private LDS region ----
    const int g = hc - 20;
    __bf16* sT = sAB + wave * 4160;  // 64 x 65
    for (int mt = 0; mt < 4; ++mt)
      for (int nt = 0; nt < 4; ++nt)
        for (int r = 0; r < 4; ++r)
          sT[(mt * 16 + quad * 4 + r) * 65 + nt * 16 + lm] =
              (__bf16)acc[mt][nt][r];
    for (int pp = 0; pp < 8; ++pp) {
      int d = pp * 8 + (lane >> 3);
      int lloc = (lane & 7) * 8;
      bf16x8 o;
      for (int j = 0; j < 8; ++j) o[j] = sT[(lloc + j) * 65 + d];
      *(bf16x8*)(Vt + (((size_t)bb * 4 + g) * 64 + d) * 1024 + l0 + lloc) = o;
    }
  }
}

// ---------------- NT GEMM (out proj): C[M,N] fp32 = A[M,K] * B[N,K]^T -------
__global__ __launch_bounds__(256, 3)
void gemm_bt(const __bf16* __restrict__ A, const __bf16* __restrict__ B,
             float* __restrict__ Cf, int M, int N, int K) {
  __shared__ __align__(16) __bf16 sA[8192];
  __shared__ __align__(16) __bf16 sB[8192];
  const int tid = threadIdx.x;
  const int wave = tid >> 6, lane = tid & 63;
  const int ntiles = N >> 7;
  const int xcd = blockIdx.x & 7, tt = blockIdx.x >> 3;
  const int bm = (tt / ntiles) * 8 + xcd, bn = tt % ntiles;
  const int wm = wave & 1, wn = wave >> 1;
  const int rowA0 = bm << 7, rowB0 = bn << 7;
  const int r8 = lane >> 3;
  const int gg = ((lane & 7) - r8) & 7;

  floatx4 acc[4][4] = {};

  for (int k0 = 0; k0 < K; k0 += 64) {
    __syncthreads();
    for (int j = 0; j < 4; ++j) {
      int c = wave * 4 + j;
      gl_lds16(A + (size_t)(rowA0 + c * 8 + r8) * K + k0 + gg * 8, sA + c * 512);
      gl_lds16(B + (size_t)(rowB0 + c * 8 + r8) * K + k0 + gg * 8, sB + c * 512);
    }
    __syncthreads();
    for (int kb = 0; kb < 64; kb += 32) {
      const int gk = (kb >> 3) + (lane >> 4);
      bf16x8 af[4], bfv[4];
      for (int t = 0; t < 4; ++t) {
        af[t]  = *(const bf16x8*)(sA + fidx8(wm * 64 + t * 16 + (lane & 15), gk));
        bfv[t] = *(const bf16x8*)(sB + fidx8(wn * 64 + t * 16 + (lane & 15), gk));
      }
      for (int mt = 0; mt < 4; ++mt)
        for (int nt = 0; nt < 4; ++nt)
          acc[mt][nt] = __builtin_amdgcn_mfma_f32_16x16x32_bf16(af[mt], bfv[nt],
                                                                acc[mt][nt], 0, 0, 0);
    }
  }
  for (int mt = 0; mt < 4; ++mt)
    for (int nt = 0; nt < 4; ++nt)
      for (int r = 0; r < 4; ++r) {
        int row = rowA0 + wm * 64 + mt * 16 + (lane >> 4) * 4 + r;
        int col = rowB0 + wn * 64 + nt * 16 + (lane & 15);
        Cf[(size_t)row * N + col] = acc[mt][nt][r];
      }
}

// ---------------- flash attention, S^T form, BM=128, BN=128 ------------------
// 1024 blocks = 4/CU. 4 waves x 32 q-rows (regs fit: r5 measured VGPR=64).
// Diagonal-swizzled staging (zero conflicts, r6-verified). Key permutation
// kappa keeps the PV A-fragment lane-local (no LDS round-trip for P).
__global__ __launch_bounds__(256, 4)
void flash(const __bf16* __restrict__ Q, const __bf16* __restrict__ K,
           const __bf16* __restrict__ Vt, __bf16* __restrict__ Oout) {
  __shared__ __align__(16) __bf16 sKV[16384];  // K halves [0,8192); V halves [8192,16384)
  __shared__ float sL[128];
  const int tid = threadIdx.x, wave = tid >> 6, lane = tid & 63;
  const int quad = lane >> 4, lm = lane & 15;
  const int qt = blockIdx.x & 7, h = (blockIdx.x >> 3) & 15, b = blockIdx.x >> 7;
  const int g = h >> 2;
  const __bf16* Qb = Q + (((size_t)b * 16 + h) * 1024 + qt * 128) * 64;
  const __bf16* Kb = K + ((size_t)b * 4 + g) * 1024 * 64;
  const __bf16* Vb = Vt + ((size_t)b * 4 + g) * 64 * 1024;

  const int r8 = lane >> 3;
  const int gg = ((lane & 7) - r8) & 7;  // diagonal staging granule

  // stage Q (128x64) through sKV[0,8192), hoist fragments
  for (int j = 0; j < 4; ++j) {
    int c = wave * 4 + j;
    gl_lds16(Qb + (size_t)(c * 8 + r8) * 64 + gg * 8, sKV + c * 512);
  }
  __syncthreads();
  bf16x8 qf[2][2];
  for (int mt = 0; mt < 2; ++mt)
    for (int hh = 0; hh < 2; ++hh)
      qf[mt][hh] = *(const bf16x8*)(sKV + fidx8(wave * 32 + mt * 16 + lm,
                                                hh * 4 + quad));

  float l_acc[2] = {0.f, 0.f};
  floatx4 accO[2][4] = {};

  for (int kt = 0; kt < 8; ++kt) {
    __syncthreads();  // prev compute's LDS reads (and qf hoist) done
    {
      int half = wave & 1;
      if (wave < 2) {  // K keys kt*128 + half*64 + 0..63
        for (int c = 0; c < 8; ++c)
          gl_lds16(Kb + (size_t)(kt * 128 + half * 64 + c * 8 + r8) * 64 + gg * 8,
                   sKV + half * 4096 + c * 512);
      } else {         // V d-rows 0..63, keys kt*128 + half*64 + 0..63
        for (int c = 0; c < 8; ++c)
          gl_lds16(Vb + (size_t)(c * 8 + r8) * 1024 + kt * 128 + half * 64 + gg * 8,
                   sKV + 8192 + half * 4096 + c * 512);
      }
    }
    __syncthreads();

    for (int h64 = 0; h64 < 2; ++h64) {
      const __bf16* sK = sKV + h64 * 4096;
      const __bf16* sV = sKV + 8192 + h64 * 4096;

      // S^T: accT[nt][mt], key = nt*16 + quad*4 + reg, q-row = mt*16 + lm
      floatx4 accT[4][2] = {};
      for (int hh = 0; hh < 2; ++hh) {
        bf16x8 kf[4];
        for (int nt = 0; nt < 4; ++nt)
          kf[nt] = *(const bf16x8*)(sK + fidx8(nt * 16 + lm, hh * 4 + quad));
        for (int nt = 0; nt < 4; ++nt)
          for (int mt = 0; mt < 2; ++mt)
            accT[nt][mt] = __builtin_amdgcn_mfma_f32_16x16x32_bf16(
                kf[nt], qf[mt][hh], accT[nt][mt], 0, 0, 0);
      }

      // p = exp(y), |y| <= 0.13 (unit q,k; Q pre-scaled by 1/8): 2-term poly
      bf16x8 pf[2][2];
      for (int nt = 0; nt < 4; ++nt)
        for (int mt = 0; mt < 2; ++mt)
          for (int r = 0; r < 4; ++r) {
            float y = accT[nt][mt][r];
            float p = fmaf(y, fmaf(y, 0.5f, 1.0f), 1.0f);
            l_acc[mt] += p;
            pf[nt >> 1][mt][(nt & 1) * 4 + r] = (__bf16)p;
          }

      // O += P*V under kappa: B-frag = two b64 reads from diagonal sV
      for (int hh = 0; hh < 2; ++hh)
        for (int dt = 0; dt < 4; ++dt) {
          int d = dt * 16 + lm;
          int kgA = hh * 4 + (quad >> 1);
          u32x2 vA = *(const u32x2*)(sV + (d * 8 + ((kgA + d) & 7)) * 8 +
                                     (quad & 1) * 4);
          u32x2 vB = *(const u32x2*)(sV + (d * 8 + ((kgA + 2 + d) & 7)) * 8 +
                                     (quad & 1) * 4);
          u32x4 vw = {vA[0], vA[1], vB[0], vB[1]};
          bf16x8 vf = __builtin_bit_cast(bf16x8, vw);
          for (int mt = 0; mt < 2; ++mt)
            accO[mt][dt] = __builtin_amdgcn_mfma_f32_16x16x32_bf16(
                pf[hh][mt], vf, accO[mt][dt], 0, 0, 0);
        }
    }
  }

  // row sums: lane (quad,lm) holds partials of row mt*16+lm; reduce quads
  for (int mt = 0; mt < 2; ++mt) {
    float l = l_acc[mt];
    l += __shfl_xor(l, 16);
    l += __shfl_xor(l, 32);
    if (quad == 0) sL[wave * 32 + mt * 16 + lm] = l;
  }
  __syncthreads();

  // accO C-layout: row = mt*16 + quad*4 + r, col(dim) = dt*16 + lm
  for (int mt = 0; mt < 2; ++mt)
    for (int r = 0; r < 4; ++r) {
      float inv = 1.f / sL[wave * 32 + mt * 16 + quad * 4 + r];
      int row = qt * 128 + wave * 32 + mt * 16 + quad * 4 + r;
      for (int dt = 0; dt < 4; ++dt) {
        int col = dt * 16 + lm;
        Oout[((size_t)b * 1024 + row) * 1024 + h * 64 + col] =
            (__bf16)(accO[mt][dt][r] * inv);
      }
    }
}

extern "C" void kernel_launch(void* const* d_in, const int* in_sizes, int n_in,
                              void* d_out, int out_size, void* d_ws, size_t ws_size,
                              hipStream_t stream) {
  const float* x     = (const float*)d_in[0];
  const float* w_qkv = (const float*)d_in[1];
  const float* w_o   = (const float*)d_in[2];
  const int*   Wp    = (const int*)d_in[4];
  float* out = (float*)d_out;
  char* ws = (char*)d_ws;

  __bf16* xb    = (__bf16*)(ws + 0);          // 16 MiB
  __bf16* attn  = (__bf16*)(ws + 0);          // alias (xb dead after gemm_qkv)
  __bf16* wqkvb = (__bf16*)(ws + 16777216);   // 3 MiB
  __bf16* wob   = (__bf16*)(ws + 19922944);   // 2 MiB
  __bf16* Qb    = (__bf16*)(ws + 22020096);   // 16 MiB
  __bf16* Kb    = (__bf16*)(ws + 38797312);   // 4 MiB
  __bf16* Vtb   = (__bf16*)(ws + 42991616);   // 4 MiB (total ~45 MiB)

  cvt_all<<<10752, 256, 0, stream>>>(x, w_qkv, w_o, (__bf16*)ws);

  gemm_qkv<<<768, 256, 0, stream>>>(xb, wqkvb, Qb, Kb, Vtb, Wp);

  flash<<<1024, 256, 0, stream>>>(Qb, Kb, Vtb, attn);

  gemm_bt<<<512, 256, 0, stream>>>(attn, wob, out, 8192, 1024, 1024);
}

// Round 8
// 201.365 us; speedup vs baseline: 1.5140x; 1.5140x over previous
//
#include <hip/hip_runtime.h>
#include <hip/hip_bf16.h>
#include <cstdint>
#include <cstddef>

// B=8, L=1024, D=1024, NUM_HEADS=16, QUERY_GROUPS=4, HEAD_DIM=64, QKV_OUT=1536

typedef __bf16 bf16x8 __attribute__((ext_vector_type(8)));
typedef __bf16 bf16x4 __attribute__((ext_vector_type(4)));
typedef float floatx4 __attribute__((ext_vector_type(4)));
typedef uint32_t u32x2 __attribute__((ext_vector_type(2)));
typedef uint32_t u32x4 __attribute__((ext_vector_type(4)));

typedef unsigned int u32_g __attribute__((address_space(1)));
typedef unsigned int u32_l __attribute__((address_space(3)));

__device__ __forceinline__ void gl_lds16(const void* g, void* l) {
  __builtin_amdgcn_global_load_lds((const u32_g*)g, (u32_l*)l, 16, 0, 0);
}

// Diagonal-swizzled LDS tile (64-col rows, 8 granules of 8 bf16) for GEMMs:
// 16B slot(row,g) = row*8 + ((g+row)&7). Zero bank conflicts (r6-verified).
__device__ __forceinline__ int fidx8(int row, int g) {
  return (row * 8 + ((g + row) & 7)) * 8;
}

#define LOG2_THETA 13.287712379549449f  // log2(10000)

// ---------------- fused fp32 -> bf16 convert (x | w_qkv | w_o) ----------------
__global__ __launch_bounds__(256)
void cvt_all(const float* __restrict__ x, const float* __restrict__ wq,
             const float* __restrict__ wo, __bf16* __restrict__ out) {
  int i = blockIdx.x * 256 + threadIdx.x;  // grid covers exactly 2752512
  float4 v;
  if (i < 2097152)      v = ((const float4*)x)[i];
  else if (i < 2490368) v = ((const float4*)wq)[i - 2097152];
  else                  v = ((const float4*)wo)[i - 2490368];
  bf16x4 o = {(__bf16)v.x, (__bf16)v.y, (__bf16)v.z, (__bf16)v.w};
  ((bf16x4*)out)[i] = o;
}

// ---------------- GEMM1 fused: qkv proj + qk-norm + RoPE2D + V transpose ----
// XCD-aware: bid&7 = XCD; each XCD owns bm = x (mod 8), sweeps bn.
__global__ __launch_bounds__(256, 3)
void gemm_qkv(const __bf16* __restrict__ A, const __bf16* __restrict__ Bw,
              __bf16* __restrict__ Q, __bf16* __restrict__ Ko,
              __bf16* __restrict__ Vt, const int* __restrict__ Wp) {
  __shared__ __align__(16) __bf16 sAB[16640];  // sA 8192 | sB 8192 | slack for sT
  __bf16* sA = sAB;
  __bf16* sB = sAB + 8192;
  const int tid = threadIdx.x, wave = tid >> 6, lane = tid & 63;
  const int quad = lane >> 4, lm = lane & 15;
  const int xcd = blockIdx.x & 7, tt = blockIdx.x >> 3;
  const int bm = (tt / 12) * 8 + xcd, bn = tt % 12;
  const int wm = wave & 1, wn = wave >> 1;
  const int rowA0 = bm << 7, rowB0 = bn << 7;
  const int r8 = lane >> 3;
  const int gg = ((lane & 7) - r8) & 7;  // staging granule for this lane

  floatx4 acc[4][4] = {};

  for (int k0 = 0; k0 < 1024; k0 += 64) {
    __syncthreads();
    for (int j = 0; j < 4; ++j) {
      int c = wave * 4 + j;
      gl_lds16(A + (size_t)(rowA0 + c * 8 + r8) * 1024 + k0 + gg * 8, sA + c * 512);
      gl_lds16(Bw + (size_t)(rowB0 + c * 8 + r8) * 1024 + k0 + gg * 8, sB + c * 512);
    }
    __syncthreads();
    for (int kb = 0; kb < 64; kb += 32) {
      const int gk = (kb >> 3) + quad;
      bf16x8 af[4], bfv[4];
      for (int t = 0; t < 4; ++t) {
        af[t]  = *(const bf16x8*)(sA + fidx8(wm * 64 + t * 16 + lm, gk));
        bfv[t] = *(const bf16x8*)(sB + fidx8(wn * 64 + t * 16 + lm, gk));
      }
      for (int mt = 0; mt < 4; ++mt)
        for (int nt = 0; nt < 4; ++nt)
          acc[mt][nt] = __builtin_amdgcn_mfma_f32_16x16x32_bf16(af[mt], bfv[nt],
                                                                acc[mt][nt], 0, 0, 0);
    }
  }

  __syncthreads();  // all waves' MFMA LDS reads done before sT reuse

  const int hc = bn * 2 + wn;       // head-chunk 0..23
  const int row0 = rowA0 + wm * 64; // this wave's first global row
  const int bb = row0 >> 10, l0 = row0 & 1023;

  if (hc < 20) {
    // ---- q/k: row-norm + RoPE, registers + shuffles ----
    const bool isq = hc < 16;
    const int W = Wp[0];
    const float invfA = exp2f(-(float)lm * 0.03125f * LOG2_THETA);
    const float invfB = exp2f(-(float)(lm + 16) * 0.03125f * LOG2_THETA);
    __bf16* base = isq
        ? Q + (((size_t)bb * 16 + hc) * 1024 + l0) * 64
        : Ko + (((size_t)bb * 4 + (hc - 16)) * 1024 + l0) * 64;
    const int srcA = (lane & 48) | ((2 * lm) & 15);  // quad*16 + (2i)&15
    const bool lo = lm < 8;
    for (int mt = 0; mt < 4; ++mt)
      for (int r = 0; r < 4; ++r) {
        float a0 = acc[mt][0][r], a1 = acc[mt][1][r];
        float a2 = acc[mt][2][r], a3 = acc[mt][3][r];
        float ss = a0 * a0 + a1 * a1 + a2 * a2 + a3 * a3;
        ss += __shfl_xor(ss, 1); ss += __shfl_xor(ss, 2);
        ss += __shfl_xor(ss, 4); ss += __shfl_xor(ss, 8);
        float rn = (isq ? 0.125f : 1.0f) / (sqrtf(ss) + 1e-10f);
        a0 *= rn; a1 *= rn; a2 *= rn; a3 *= rn;
        float e0 = __shfl(a0, srcA),     e1 = __shfl(a1, srcA);
        float f0 = __shfl(a0, srcA + 1), f1 = __shfl(a1, srcA + 1);
        float g0 = __shfl(a2, srcA),     g1 = __shfl(a3, srcA);
        float h0 = __shfl(a2, srcA + 1), h1 = __shfl(a3, srcA + 1);
        float x1A = lo ? e0 : e1, x2A = lo ? f0 : f1;
        float x1B = lo ? g0 : g1, x2B = lo ? h0 : h1;
        int lrow = l0 + mt * 16 + quad * 4 + r;
        int pos = lrow / W + lrow % W;
        float fA = (float)pos * invfA, fB = (float)pos * invfB;
        float cA = __cosf(fA), sA_ = __sinf(fA);
        float cB = __cosf(fB), sB_ = __sinf(fB);
        __bf16* dst = base + (size_t)(mt * 16 + quad * 4 + r) * 64;
        dst[lm]      = (__bf16)(x1A * cA - x2A * sA_);
        dst[lm + 16] = (__bf16)(x1B * cB - x2B * sB_);
        dst[lm + 32] = (__bf16)(x1A * sA_ + x2A * cA);
        dst[lm + 48] = (__bf16)(x1B * sB_ + x2B * cB);
      }
  } else {
    // ---- v: transpose 64x64 tile through wave-private LDS region ----
    const int g = hc - 20;
    __bf16* sT = sAB + wave * 4160;  // 64 x 65
    for (int mt = 0; mt < 4; ++mt)
      for (int nt = 0; nt < 4; ++nt)
        for (int r = 0; r < 4; ++r)
          sT[(mt * 16 + quad * 4 + r) * 65 + nt * 16 + lm] =
              (__bf16)acc[mt][nt][r];
    for (int pp = 0; pp < 8; ++pp) {
      int d = pp * 8 + (lane >> 3);
      int lloc = (lane & 7) * 8;
      bf16x8 o;
      for (int j = 0; j < 8; ++j) o[j] = sT[(lloc + j) * 65 + d];
      *(bf16x8*)(Vt + (((size_t)bb * 4 + g) * 64 + d) * 1024 + l0 + lloc) = o;
    }
  }
}

// ---------------- NT GEMM (out proj): C[M,N] fp32 = A[M,K] * B[N,K]^T -------
__global__ __launch_bounds__(256, 3)
void gemm_bt(const __bf16* __restrict__ A, const __bf16* __restrict__ B,
             float* __restrict__ Cf, int M, int N, int K) {
  __shared__ __align__(16) __bf16 sA[8192];
  __shared__ __align__(16) __bf16 sB[8192];
  const int tid = threadIdx.x;
  const int wave = tid >> 6, lane = tid & 63;
  const int ntiles = N >> 7;
  const int xcd = blockIdx.x & 7, tt = blockIdx.x >> 3;
  const int bm = (tt / ntiles) * 8 + xcd, bn = tt % ntiles;
  const int wm = wave & 1, wn = wave >> 1;
  const int rowA0 = bm << 7, rowB0 = bn << 7;
  const int r8 = lane >> 3;
  const int gg = ((lane & 7) - r8) & 7;

  floatx4 acc[4][4] = {};

  for (int k0 = 0; k0 < K; k0 += 64) {
    __syncthreads();
    for (int j = 0; j < 4; ++j) {
      int c = wave * 4 + j;
      gl_lds16(A + (size_t)(rowA0 + c * 8 + r8) * K + k0 + gg * 8, sA + c * 512);
      gl_lds16(B + (size_t)(rowB0 + c * 8 + r8) * K + k0 + gg * 8, sB + c * 512);
    }
    __syncthreads();
    for (int kb = 0; kb < 64; kb += 32) {
      const int gk = (kb >> 3) + (lane >> 4);
      bf16x8 af[4], bfv[4];
      for (int t = 0; t < 4; ++t) {
        af[t]  = *(const bf16x8*)(sA + fidx8(wm * 64 + t * 16 + (lane & 15), gk));
        bfv[t] = *(const bf16x8*)(sB + fidx8(wn * 64 + t * 16 + (lane & 15), gk));
      }
      for (int mt = 0; mt < 4; ++mt)
        for (int nt = 0; nt < 4; ++nt)
          acc[mt][nt] = __builtin_amdgcn_mfma_f32_16x16x32_bf16(af[mt], bfv[nt],
                                                                acc[mt][nt], 0, 0, 0);
    }
  }
  for (int mt = 0; mt < 4; ++mt)
    for (int nt = 0; nt < 4; ++nt)
      for (int r = 0; r < 4; ++r) {
        int row = rowA0 + wm * 64 + mt * 16 + (lane >> 4) * 4 + r;
        int col = rowB0 + wn * 64 + nt * 16 + (lane & 15);
        Cf[(size_t)row * N + col] = acc[mt][nt][r];
      }
}

// ---------------- flash attention (round-5 body, 52 us verified) -------------
// S^T form, BM=128, BN=128 (two 64-key halves per stage), XOR-granule swizzle.
// XCD-affine grid: all 32 blocks of one (b,g) land on one XCD so K+V are
// fetched into that XCD's L2 exactly once (structural locality, not LLC luck).
__global__ __launch_bounds__(256, 4)
void flash(const __bf16* __restrict__ Q, const __bf16* __restrict__ K,
           const __bf16* __restrict__ Vt, __bf16* __restrict__ Oout) {
  __shared__ __align__(16) __bf16 sKV[16384];  // K halves [0,8192); V halves [8192,16384)
  __shared__ float sL[128];
  const int tid = threadIdx.x, wave = tid >> 6, lane = tid & 63;
  const int quad = lane >> 4, lm = lane & 15;
  // XCD-affine decode: xcd = bid&7 owns bg in {xcd, xcd+8, xcd+16, xcd+24}
  const int xcd = blockIdx.x & 7, u = blockIdx.x >> 3;
  const int bg = xcd + 8 * (u & 3);       // 0..31
  const int b = bg >> 2, g = bg & 3;
  const int inner = u >> 2;               // 0..31
  const int h = g * 4 + (inner >> 3);
  const int qt = inner & 7;
  const __bf16* Qb = Q + (((size_t)b * 16 + h) * 1024 + qt * 128) * 64;
  const __bf16* Kb = K + ((size_t)b * 4 + g) * 1024 * 64;
  const __bf16* Vb = Vt + ((size_t)b * 4 + g) * 64 * 1024;

  const int r8 = lane >> 3;
  const int gsw = (lane & 7) ^ r8;  // XOR-granule staging swizzle (r5)

  // stage Q (128x64) through sKV[0,8192), hoist fragments
  for (int j = 0; j < 4; ++j) {
    int c = wave * 4 + j;
    gl_lds16(Qb + (size_t)(c * 8 + r8) * 64 + gsw * 8, sKV + c * 512);
  }
  __syncthreads();
  bf16x8 qf[2][2];
  for (int mt = 0; mt < 2; ++mt)
    for (int hh = 0; hh < 2; ++hh) {
      int r = wave * 32 + mt * 16 + lm;
      qf[mt][hh] = *(const bf16x8*)(sKV + (r >> 3) * 512 + (r & 7) * 64 +
                                    (((hh * 4 + quad) ^ (r & 7)) * 8));
    }

  float l_acc[2] = {0.f, 0.f};
  floatx4 accO[2][4] = {};

  for (int kt = 0; kt < 8; ++kt) {
    __syncthreads();  // prev compute's LDS reads (and qf hoist) done
    {
      int half = wave & 1;
      if (wave < 2) {  // K keys kt*128 + half*64 + 0..63
        for (int c = 0; c < 8; ++c)
          gl_lds16(Kb + (size_t)(kt * 128 + half * 64 + c * 8 + r8) * 64 + gsw * 8,
                   sKV + half * 4096 + c * 512);
      } else {         // V d-rows 0..63, keys kt*128 + half*64 + 0..63
        for (int c = 0; c < 8; ++c)
          gl_lds16(Vb + (size_t)(c * 8 + r8) * 1024 + kt * 128 + half * 64 + gsw * 8,
                   sKV + 8192 + half * 4096 + c * 512);
      }
    }
    __syncthreads();

    for (int h64 = 0; h64 < 2; ++h64) {
      const __bf16* sK = sKV + h64 * 4096;
      const __bf16* sV = sKV + 8192 + h64 * 4096;

      // S^T: accT[nt][mt], key = nt*16 + quad*4 + reg, q-row = mt*16 + lm
      floatx4 accT[4][2] = {};
      for (int hh = 0; hh < 2; ++hh) {
        bf16x8 kf[4];
        for (int nt = 0; nt < 4; ++nt) {
          int r = nt * 16 + lm;
          kf[nt] = *(const bf16x8*)(sK + (r >> 3) * 512 + (r & 7) * 64 +
                                    (((hh * 4 + quad) ^ (r & 7)) * 8));
        }
        for (int nt = 0; nt < 4; ++nt)
          for (int mt = 0; mt < 2; ++mt)
            accT[nt][mt] = __builtin_amdgcn_mfma_f32_16x16x32_bf16(
                kf[nt], qf[mt][hh], accT[nt][mt], 0, 0, 0);
      }

      // p = exp(y), |y| <= 0.13 (unit q,k; Q pre-scaled by 1/8): 2-term poly
      bf16x8 pf[2][2];
      for (int nt = 0; nt < 4; ++nt)
        for (int mt = 0; mt < 2; ++mt)
          for (int r = 0; r < 4; ++r) {
            float y = accT[nt][mt][r];
            float p = fmaf(y, fmaf(y, 0.5f, 1.0f), 1.0f);
            l_acc[mt] += p;
            pf[nt >> 1][mt][(nt & 1) * 4 + r] = (__bf16)p;
          }

      // O += P*V under kappa: B-frag = two b64 reads from XOR-swizzled sV
      for (int hh = 0; hh < 2; ++hh)
        for (int dt = 0; dt < 4; ++dt) {
          int r = dt * 16 + lm;
          int rowoff = (r >> 3) * 512 + (r & 7) * 64;
          int lgA = hh * 4 + (quad >> 1);
          u32x2 vA = *(const u32x2*)(sV + rowoff + ((lgA ^ (r & 7)) * 8) + (quad & 1) * 4);
          u32x2 vB = *(const u32x2*)(sV + rowoff + (((lgA + 2) ^ (r & 7)) * 8) + (quad & 1) * 4);
          u32x4 vw = {vA[0], vA[1], vB[0], vB[1]};
          bf16x8 vf = __builtin_bit_cast(bf16x8, vw);
          for (int mt = 0; mt < 2; ++mt)
            accO[mt][dt] = __builtin_amdgcn_mfma_f32_16x16x32_bf16(
                pf[hh][mt], vf, accO[mt][dt], 0, 0, 0);
        }
    }
  }

  // row sums: lane (quad,lm) holds partials of row mt*16+lm; reduce quads
  for (int mt = 0; mt < 2; ++mt) {
    float l = l_acc[mt];
    l += __shfl_xor(l, 16);
    l += __shfl_xor(l, 32);
    if (quad == 0) sL[wave * 32 + mt * 16 + lm] = l;
  }
  __syncthreads();

  // accO C-layout: row = mt*16 + quad*4 + r, col(dim) = dt*16 + lm
  for (int mt = 0; mt < 2; ++mt)
    for (int r = 0; r < 4; ++r) {
      float inv = 1.f / sL[wave * 32 + mt * 16 + quad * 4 + r];
      int row = qt * 128 + wave * 32 + mt * 16 + quad * 4 + r;
      for (int dt = 0; dt < 4; ++dt) {
        int col = dt * 16 + lm;
        Oout[((size_t)b * 1024 + row) * 1024 + h * 64 + col] =
            (__bf16)(accO[mt][dt][r] * inv);
      }
    }
}

extern "C" void kernel_launch(void* const* d_in, const int* in_sizes, int n_in,
                              void* d_out, int out_size, void* d_ws, size_t ws_size,
                              hipStream_t stream) {
  const float* x     = (const float*)d_in[0];
  const float* w_qkv = (const float*)d_in[1];
  const float* w_o   = (const float*)d_in[2];
  const int*   Wp    = (const int*)d_in[4];
  float* out = (float*)d_out;
  char* ws = (char*)d_ws;

  __bf16* xb    = (__bf16*)(ws + 0);          // 16 MiB
  __bf16* attn  = (__bf16*)(ws + 0);          // alias (xb dead after gemm_qkv)
  __bf16* wqkvb = (__bf16*)(ws + 16777216);   // 3 MiB
  __bf16* wob   = (__bf16*)(ws + 19922944);   // 2 MiB
  __bf16* Qb    = (__bf16*)(ws + 22020096);   // 16 MiB
  __bf16* Kb    = (__bf16*)(ws + 38797312);   // 4 MiB
  __bf16* Vtb   = (__bf16*)(ws + 42991616);   // 4 MiB (total ~45 MiB)

  cvt_all<<<10752, 256, 0, stream>>>(x, w_qkv, w_o, (__bf16*)ws);

  gemm_qkv<<<768, 256, 0, stream>>>(xb, wqkvb, Qb, Kb, Vtb, Wp);

  flash<<<1024, 256, 0, stream>>>(Qb, Kb, Vtb, attn);

  gemm_bt<<<512, 256, 0, stream>>>(attn, wob, out, 8192, 1024, 1024);
}